// Round 1
// baseline (989.976 us; speedup 1.0000x reference)
//
#include <hip/hip_runtime.h>

// PatientMeanEncoder: causal nonzero-mean pool over concat(timesteps, MLP(dem)).
// N=64, L=2048, C_IN=256, DEM=10, hidden 40 -> 20, C_OUT = 276.
//
// R6: single-pass chained scan. The 3-kernel version read ts twice from HBM
// (134 MB extra) and serialized through a latency-bound prefix kernel. Here
// each wave owns one (n, seg) of 64 rows: stream ts once computing segment
// {sum,cnt} totals, chain the exclusive prefix through agent-scope atomics
// (ticket-ordered -> deadlock-free regardless of dispatch order), then
// recompute the running mean from the (now MALL-resident) rows and NT-store
// the output. dem channels are constant along l, so their causal nonzero-mean
// is the MLP output itself.

#define NB 64
#define LL 2048
#define CIN 256
#define COUT 276
#define DEMD 10
#define H1 40
#define H2 20

#define FSEG 32              // segments per n (chain depth)
#define FLSEG (LL / FSEG)    // 64 rows per segment
#define FUB 8                // rows per prefetch batch
#define FNB (FLSEG / FUB)    // 8 batches
#define NUNITS (NB * FSEG)   // 2048 waves
#define NBLK (NUNITS / 4)    // 512 blocks

typedef float vfloat4 __attribute__((ext_vector_type(4)));

static __device__ __forceinline__ void nt_store4(float* p, float4 v) {
    vfloat4 t = {v.x, v.y, v.z, v.w};
    __builtin_nontemporal_store(t, (vfloat4*)p);
}

static __device__ __forceinline__ unsigned long long packsc(float s, float c) {
    union { float f[2]; unsigned long long u; } t;
    t.f[0] = s; t.f[1] = c;
    return t.u;
}

static __device__ __forceinline__ float2 unpacksc(unsigned long long u) {
    union { float f[2]; unsigned long long uu; } t;
    t.uu = u;
    return make_float2(t.f[0], t.f[1]);
}

__global__ __launch_bounds__(256) void pme_fused(
    const float* __restrict__ ts,   // (N, L, 256)
    const float* __restrict__ dem,  // (N, 10)
    const float* __restrict__ W1, const float* __restrict__ b1,
    const float* __restrict__ W2, const float* __restrict__ b2,
    float* __restrict__ out,        // (N, L, 276)
    unsigned int* __restrict__ tick,        // ws byte 0
    unsigned int* __restrict__ flags,       // ws byte 4096, NB*FSEG uints
    unsigned long long* __restrict__ payload) // ws byte 16384, (n,seg,256) u64 {sum,cnt}
{
    // Ticket: first-arriving blocks take the lowest segments -> every wave
    // only waits on a block that has already started. Deadlock-free even if
    // only one block were resident.
    __shared__ unsigned int s_t;
    if (threadIdx.x == 0)
        s_t = atomicAdd(tick, 1u) & (NBLK - 1);
    __syncthreads();

    const int tid  = threadIdx.x;
    const int w    = tid >> 6;
    const int lane = tid & 63;
    const int g    = (int)s_t * 4 + w;   // unit = seg*NB + n (4 waves share a seg)
    const int n    = g & (NB - 1);
    const int seg  = g >> 6;

    const float4* tp = (const float4*)(ts + ((size_t)n * LL + seg * FLSEG) * CIN) + lane;

    // ---------------- phase A: segment totals (single HBM read) ----------------
    float4 sum = make_float4(0.f, 0.f, 0.f, 0.f);
    float4 ctv = make_float4(0.f, 0.f, 0.f, 0.f);
    {
        float4 v[2][FUB];
#pragma unroll
        for (int u = 0; u < FUB; ++u)
            v[0][u] = tp[(size_t)u * (CIN / 4)];
        for (int bb = 0; bb < FNB; ++bb) {
            const int cur = bb & 1;
            if (bb + 1 < FNB) {
#pragma unroll
                for (int u = 0; u < FUB; ++u)
                    v[cur ^ 1][u] = tp[(size_t)((bb + 1) * FUB + u) * (CIN / 4)];
            }
#pragma unroll
            for (int u = 0; u < FUB; ++u) {
                float4 x = v[cur][u];
                sum.x += x.x; ctv.x += (x.x != 0.f) ? 1.f : 0.f;
                sum.y += x.y; ctv.y += (x.y != 0.f) ? 1.f : 0.f;
                sum.z += x.z; ctv.z += (x.z != 0.f) ? 1.f : 0.f;
                sum.w += x.w; ctv.w += (x.w != 0.f) ? 1.f : 0.f;
            }
        }
    }

    // ---------------- chain: receive exclusive prefix, publish inclusive ------
    // Payload is 8B relaxed-agent atomics (write-through to the coherence
    // point), flag is release/acquire at agent scope: per-XCD L2s are not
    // cross-coherent, so nothing here relies on plain-cached traffic.
    float psum[4] = {0.f, 0.f, 0.f, 0.f};
    float pcnt[4] = {0.f, 0.f, 0.f, 0.f};
    if (seg > 0) {
        const unsigned int* fl = flags + (n * FSEG + seg - 1);
        while (__hip_atomic_load(fl, __ATOMIC_ACQUIRE, __HIP_MEMORY_SCOPE_AGENT) == 0u)
            __builtin_amdgcn_s_sleep(2);
        const unsigned long long* pp = payload + (size_t)(n * FSEG + seg - 1) * 256 + lane * 4;
#pragma unroll
        for (int j = 0; j < 4; ++j) {
            float2 sc = unpacksc(__hip_atomic_load(pp + j, __ATOMIC_RELAXED, __HIP_MEMORY_SCOPE_AGENT));
            psum[j] = sc.x; pcnt[j] = sc.y;
        }
    }
    if (seg < FSEG - 1) {
        unsigned long long* ps = payload + (size_t)(n * FSEG + seg) * 256 + lane * 4;
        const float ls[4] = {sum.x, sum.y, sum.z, sum.w};
        const float lc[4] = {ctv.x, ctv.y, ctv.z, ctv.w};
#pragma unroll
        for (int j = 0; j < 4; ++j)
            __hip_atomic_store(ps + j, packsc(psum[j] + ls[j], pcnt[j] + lc[j]),
                               __ATOMIC_RELAXED, __HIP_MEMORY_SCOPE_AGENT);
        __threadfence();
        if (lane == 0)
            __hip_atomic_store(flags + (n * FSEG + seg), 1u,
                               __ATOMIC_RELEASE, __HIP_MEMORY_SCOPE_AGENT);
    }

    // ---------------- dem MLP (off the chain's critical path) ----------------
    const float* dn = dem + n * DEMD;
    float4 e4q = make_float4(0.f, 0.f, 0.f, 0.f);
    {
        float h[H1];
#pragma unroll
        for (int k = 0; k < H1; ++k) {
            float hk = b1[k];
#pragma unroll
            for (int i = 0; i < DEMD; ++i)
                hk += dn[i] * W1[i * H1 + k];
            h[k] = fmaxf(hk, 0.f);
        }
        const int q = (lane < 5) ? lane : 0;
        float e0 = b2[q * 4 + 0], e1 = b2[q * 4 + 1], e2 = b2[q * 4 + 2], e3 = b2[q * 4 + 3];
#pragma unroll
        for (int k = 0; k < H1; ++k) {
            e0 += h[k] * W2[k * H2 + q * 4 + 0];
            e1 += h[k] * W2[k * H2 + q * 4 + 1];
            e2 += h[k] * W2[k * H2 + q * 4 + 2];
            e3 += h[k] * W2[k * H2 + q * 4 + 3];
        }
        e4q = make_float4(fmaxf(e0, 0.f), fmaxf(e1, 0.f), fmaxf(e2, 0.f), fmaxf(e3, 0.f));
    }

    // ---------------- output phase: re-read rows (MALL-resident), scan, store --
    float4 acc = make_float4(psum[0], psum[1], psum[2], psum[3]);
    float4 cnt = make_float4(pcnt[0], pcnt[1], pcnt[2], pcnt[3]);

    float* oprow = out + ((size_t)n * LL + seg * FLSEG) * COUT;

    float4 v[2][FUB];
#pragma unroll
    for (int u = 0; u < FUB; ++u)
        v[0][u] = tp[(size_t)u * (CIN / 4)];

    for (int bb = 0; bb < FNB; ++bb) {
        const int cur = bb & 1;
        if (bb + 1 < FNB) {
#pragma unroll
            for (int u = 0; u < FUB; ++u)
                v[cur ^ 1][u] = tp[(size_t)((bb + 1) * FUB + u) * (CIN / 4)];
        }
#pragma unroll
        for (int u = 0; u < FUB; ++u) {
            float4 x = v[cur][u];
            float4 r;
            acc.x += x.x; cnt.x += (x.x != 0.f) ? 1.f : 0.f;
            acc.y += x.y; cnt.y += (x.y != 0.f) ? 1.f : 0.f;
            acc.z += x.z; cnt.z += (x.z != 0.f) ? 1.f : 0.f;
            acc.w += x.w; cnt.w += (x.w != 0.f) ? 1.f : 0.f;
            r.x = fmaxf(acc.x * __builtin_amdgcn_rcpf(fmaxf(cnt.x, 1.f)), 0.f);
            r.y = fmaxf(acc.y * __builtin_amdgcn_rcpf(fmaxf(cnt.y, 1.f)), 0.f);
            r.z = fmaxf(acc.z * __builtin_amdgcn_rcpf(fmaxf(cnt.z, 1.f)), 0.f);
            r.w = fmaxf(acc.w * __builtin_amdgcn_rcpf(fmaxf(cnt.w, 1.f)), 0.f);
            float* rowp = oprow + (size_t)(bb * FUB + u) * COUT;
            nt_store4(rowp + lane * 4, r);             // channels 0..255
            if (lane < 5)
                nt_store4(rowp + CIN + lane * 4, e4q); // channels 256..275
        }
    }
}

extern "C" void kernel_launch(void* const* d_in, const int* in_sizes, int n_in,
                              void* d_out, int out_size, void* d_ws, size_t ws_size,
                              hipStream_t stream) {
    const float* ts  = (const float*)d_in[0];
    const float* dem = (const float*)d_in[1];
    const float* W1  = (const float*)d_in[2];
    const float* b1  = (const float*)d_in[3];
    const float* W2  = (const float*)d_in[4];
    const float* b2  = (const float*)d_in[5];
    float* out = (float*)d_out;
    float* ws  = (float*)d_ws;

    // ws layout: [0,4): ticket counter; [4096,12288): flags (2048 u32);
    //            [16384, 16384+4MB): payload (2048 units * 256 u64 {sum,cnt}).
    hipMemsetAsync(d_ws, 0, 16384, stream);   // zero ticket + flags each launch

    pme_fused<<<NBLK, 256, 0, stream>>>(
        ts, dem, W1, b1, W2, b2, out,
        (unsigned int*)ws,
        (unsigned int*)(ws + 1024),
        (unsigned long long*)(ws + 4096));
}

// Round 2
// 426.542 us; speedup vs baseline: 2.3209x; 2.3209x over previous
//
#include <hip/hip_runtime.h>

// PatientMeanEncoder: causal nonzero-mean pool over concat(timesteps, MLP(dem)).
// N=64, L=2048, C_IN=256, DEM=10, hidden 40 -> 20, C_OUT = 276.
//
// R7: single kernel, one 1024-thread block per patient (n). The R6 chained
// scan was latency-poisoned: agent-scope acquire polling emits buffer_inv
// per iteration (per-XCD L2s non-coherent), turning each chain hop into
// ~25 us of invalidation storms (901 us total, 470 GB/s, 2.7% VALUBusy).
// Fix: keep the L-prefix entirely inside one workgroup. Wave w of 16 owns
// 128 rows; phase A streams its chunk once from HBM accumulating {sum,cnt};
// an LDS exclusive prefix over the 16 waves (one __syncthreads) replaces
// all cross-block sync; phase B re-reads the chunk (MALL-resident, 134 MB
// < 256 MB L3) and NT-stores the output so `out` doesn't evict `ts`.
// No atomics, no fences, no workspace, one launch.
//
// dem channels are constant along l, so causal nonzero-mean == the MLP
// output itself (v>0: (l+1)v/(l+1)=v; v==0: 0/max(0,1)=0).

#define NB 64
#define LL 2048
#define CIN 256
#define COUT 276
#define DEMD 10
#define H1 40
#define H2 20

#define WAVES 16
#define ROWS (LL / WAVES)    // 128 rows per wave
#define UB 8                 // rows per prefetch batch (8 KB in flight / wave)
#define NBATCH (ROWS / UB)   // 16

typedef float vfloat4 __attribute__((ext_vector_type(4)));

static __device__ __forceinline__ void nt_store4(float* p, float4 v) {
    vfloat4 t = {v.x, v.y, v.z, v.w};
    __builtin_nontemporal_store(t, (vfloat4*)p);
}

__global__ __launch_bounds__(1024) void pme_onepass(
    const float* __restrict__ ts,   // (N, L, 256)
    const float* __restrict__ dem,  // (N, 10)
    const float* __restrict__ W1, const float* __restrict__ b1,
    const float* __restrict__ W2, const float* __restrict__ b2,
    float* __restrict__ out)        // (N, L, 276)
{
    __shared__ float4 LS[WAVES][64];   // per-wave chunk sums   (16 KB)
    __shared__ float4 LC[WAVES][64];   // per-wave chunk counts (16 KB)

    const int tid  = threadIdx.x;
    const int w    = tid >> 6;
    const int lane = tid & 63;
    const int n    = blockIdx.x;

    const float4* tp = (const float4*)(ts + ((size_t)n * LL + w * ROWS) * CIN) + lane;

    // ---------------- phase A: chunk totals (the only HBM read of ts) -------
    float4 sum = make_float4(0.f, 0.f, 0.f, 0.f);
    float4 ctv = make_float4(0.f, 0.f, 0.f, 0.f);
    {
        float4 v[2][UB];
#pragma unroll
        for (int u = 0; u < UB; ++u)
            v[0][u] = tp[(size_t)u * (CIN / 4)];
        for (int bb = 0; bb < NBATCH; ++bb) {
            const int cur = bb & 1;
            if (bb + 1 < NBATCH) {
#pragma unroll
                for (int u = 0; u < UB; ++u)
                    v[cur ^ 1][u] = tp[(size_t)((bb + 1) * UB + u) * (CIN / 4)];
            }
#pragma unroll
            for (int u = 0; u < UB; ++u) {
                float4 x = v[cur][u];
                sum.x += x.x; ctv.x += (x.x != 0.f) ? 1.f : 0.f;
                sum.y += x.y; ctv.y += (x.y != 0.f) ? 1.f : 0.f;
                sum.z += x.z; ctv.z += (x.z != 0.f) ? 1.f : 0.f;
                sum.w += x.w; ctv.w += (x.w != 0.f) ? 1.f : 0.f;
            }
        }
    }

    LS[w][lane] = sum;
    LC[w][lane] = ctv;
    __syncthreads();

    // ---------------- exclusive prefix over the 16 wave-chunks --------------
    float4 acc = make_float4(0.f, 0.f, 0.f, 0.f);
    float4 cnt = make_float4(0.f, 0.f, 0.f, 0.f);
    for (int s = 0; s < w; ++s) {           // wave-uniform trip count
        float4 a = LS[s][lane];
        float4 c = LC[s][lane];
        acc.x += a.x; acc.y += a.y; acc.z += a.z; acc.w += a.w;
        cnt.x += c.x; cnt.y += c.y; cnt.z += c.z; cnt.w += c.w;
    }

    // ---------------- dem MLP (no h[] array -> low register pressure) -------
    float4 e4q;
    {
        const float* dn = dem + n * DEMD;
        float d[DEMD];
#pragma unroll
        for (int i = 0; i < DEMD; ++i)
            d[i] = dn[i];
        const int q = (lane < 5) ? lane : 0;
        float e0 = b2[q * 4 + 0], e1 = b2[q * 4 + 1], e2 = b2[q * 4 + 2], e3 = b2[q * 4 + 3];
#pragma unroll
        for (int k = 0; k < H1; ++k) {
            float hk = b1[k];
#pragma unroll
            for (int i = 0; i < DEMD; ++i)
                hk += d[i] * W1[i * H1 + k];
            hk = fmaxf(hk, 0.f);
            e0 += hk * W2[k * H2 + q * 4 + 0];
            e1 += hk * W2[k * H2 + q * 4 + 1];
            e2 += hk * W2[k * H2 + q * 4 + 2];
            e3 += hk * W2[k * H2 + q * 4 + 3];
        }
        e4q = make_float4(fmaxf(e0, 0.f), fmaxf(e1, 0.f), fmaxf(e2, 0.f), fmaxf(e3, 0.f));
    }

    // ---------------- phase B: re-read chunk (MALL-resident), scan, store ---
    float* oprow = out + ((size_t)n * LL + w * ROWS) * COUT;

    float4 v[2][UB];
#pragma unroll
    for (int u = 0; u < UB; ++u)
        v[0][u] = tp[(size_t)u * (CIN / 4)];

    for (int bb = 0; bb < NBATCH; ++bb) {
        const int cur = bb & 1;
        if (bb + 1 < NBATCH) {
#pragma unroll
            for (int u = 0; u < UB; ++u)
                v[cur ^ 1][u] = tp[(size_t)((bb + 1) * UB + u) * (CIN / 4)];
        }
#pragma unroll
        for (int u = 0; u < UB; ++u) {
            float4 x = v[cur][u];
            float4 r;
            acc.x += x.x; cnt.x += (x.x != 0.f) ? 1.f : 0.f;
            acc.y += x.y; cnt.y += (x.y != 0.f) ? 1.f : 0.f;
            acc.z += x.z; cnt.z += (x.z != 0.f) ? 1.f : 0.f;
            acc.w += x.w; cnt.w += (x.w != 0.f) ? 1.f : 0.f;
            r.x = fmaxf(acc.x * __builtin_amdgcn_rcpf(fmaxf(cnt.x, 1.f)), 0.f);
            r.y = fmaxf(acc.y * __builtin_amdgcn_rcpf(fmaxf(cnt.y, 1.f)), 0.f);
            r.z = fmaxf(acc.z * __builtin_amdgcn_rcpf(fmaxf(cnt.z, 1.f)), 0.f);
            r.w = fmaxf(acc.w * __builtin_amdgcn_rcpf(fmaxf(cnt.w, 1.f)), 0.f);
            float* rowp = oprow + (size_t)(bb * UB + u) * COUT;
            nt_store4(rowp + lane * 4, r);             // channels 0..255
            if (lane < 5)
                nt_store4(rowp + CIN + lane * 4, e4q); // channels 256..275
        }
    }
}

extern "C" void kernel_launch(void* const* d_in, const int* in_sizes, int n_in,
                              void* d_out, int out_size, void* d_ws, size_t ws_size,
                              hipStream_t stream) {
    const float* ts  = (const float*)d_in[0];
    const float* dem = (const float*)d_in[1];
    const float* W1  = (const float*)d_in[2];
    const float* b1  = (const float*)d_in[3];
    const float* W2  = (const float*)d_in[4];
    const float* b2  = (const float*)d_in[5];
    float* out = (float*)d_out;

    pme_onepass<<<NB, 1024, 0, stream>>>(ts, dem, W1, b1, W2, b2, out);
}

// Round 3
// 286.646 us; speedup vs baseline: 3.4536x; 1.4880x over previous
//
#include <hip/hip_runtime.h>

// PatientMeanEncoder: causal nonzero-mean pool over concat(timesteps, MLP(dem)).
// N=64, L=2048, C_IN=256, DEM=10, hidden 40 -> 20, C_OUT = 276.
//
// R8: full-chip two-pass. R7 (one block per patient) was per-CU-BW saturated
// (23.4 GB/s/CU == the 6.3TB/s / 256CU ceiling) with 192 CUs idle. R6's
// cross-block chain was latency-poisoned by agent-scope acquire polling.
// Fix: k1 writes (n, 32-row-segment) {sum,cnt} partials with 4096 waves
// (16 waves/CU, full chip); k2 (same grid) lets EACH WAVE sum the <=63
// preceding partials itself (8 MB array, L2/MALL-resident, coalesced) --
// no serial prefix kernel, no atomics, no grid sync. k2 then re-reads its
// 32 rows (MALL-resident after k1: FETCH stayed at 134 MB in R7, proving
// the re-read never touches HBM) and NT-stores so `out` doesn't evict ts.
//
// dem channels are constant along l, so causal nonzero-mean == the MLP
// output itself (v>0: (l+1)v/(l+1)=v; v==0: 0/max(0,1)=0).

#define NB 64
#define LL 2048
#define CIN 256
#define COUT 276
#define DEMD 10
#define H1 40
#define H2 20

#define SEGS 64              // segments per patient
#define SROWS (LL / SEGS)    // 32 rows per segment
#define UB 8                 // rows per prefetch batch (8 KB in flight / wave)
#define NBATCH (SROWS / UB)  // 4
#define NUNITS (NB * SEGS)   // 4096 waves
#define NBLK (NUNITS / 4)    // 1024 blocks

typedef float vfloat4 __attribute__((ext_vector_type(4)));

static __device__ __forceinline__ void nt_store4(float* p, float4 v) {
    vfloat4 t = {v.x, v.y, v.z, v.w};
    __builtin_nontemporal_store(t, (vfloat4*)p);
}

// ---------------- kernel 1: per-segment {sum,cnt} partials ----------------
__global__ __launch_bounds__(256) void pme_part(
    const float* __restrict__ ts,   // (N, L, 256)
    float* __restrict__ part)       // (N, SEGS, 256) x {sum, cnt}
{
    const int tid  = threadIdx.x;
    const int w    = tid >> 6;
    const int lane = tid & 63;

    const int unit = blockIdx.x * 4 + w;
    const int seg  = unit & (SEGS - 1);
    const int n    = unit >> 6;

    const float4* tp = (const float4*)(ts + ((size_t)n * LL + seg * SROWS) * CIN) + lane;

    float4 sum = make_float4(0.f, 0.f, 0.f, 0.f);
    float4 ctv = make_float4(0.f, 0.f, 0.f, 0.f);

    float4 v[2][UB];
#pragma unroll
    for (int u = 0; u < UB; ++u)
        v[0][u] = tp[(size_t)u * (CIN / 4)];

    for (int bb = 0; bb < NBATCH; ++bb) {
        const int cur = bb & 1;
        if (bb + 1 < NBATCH) {
#pragma unroll
            for (int u = 0; u < UB; ++u)
                v[cur ^ 1][u] = tp[(size_t)((bb + 1) * UB + u) * (CIN / 4)];
        }
#pragma unroll
        for (int u = 0; u < UB; ++u) {
            float4 x = v[cur][u];
            sum.x += x.x; ctv.x += (x.x != 0.f) ? 1.f : 0.f;
            sum.y += x.y; ctv.y += (x.y != 0.f) ? 1.f : 0.f;
            sum.z += x.z; ctv.z += (x.z != 0.f) ? 1.f : 0.f;
            sum.w += x.w; ctv.w += (x.w != 0.f) ? 1.f : 0.f;
        }
    }

    // interleaved {sum,cnt} per channel pair: direct float4 accumulation in k2
    float4* pp = (float4*)part + ((size_t)n * SEGS + seg) * 128 + lane * 2;
    pp[0] = make_float4(sum.x, ctv.x, sum.y, ctv.y);
    pp[1] = make_float4(sum.z, ctv.z, sum.w, ctv.w);
}

// ------- kernel 2: per-wave exclusive prefix + scan + fused dem write -----
__global__ __launch_bounds__(256) void pme_scan(
    const float* __restrict__ ts,   // (N, L, 256)
    const float* __restrict__ part, // (N, SEGS, 256) x {sum, cnt}
    const float* __restrict__ dem,  // (N, 10)
    const float* __restrict__ W1, const float* __restrict__ b1,
    const float* __restrict__ W2, const float* __restrict__ b2,
    float* __restrict__ out)        // (N, L, 276)
{
    const int tid  = threadIdx.x;
    const int w    = tid >> 6;
    const int lane = tid & 63;

    const int unit = blockIdx.x * 4 + w;
    const int seg  = unit & (SEGS - 1);
    const int n    = unit >> 6;

    // ---- exclusive prefix: sum the preceding partials (L2/MALL-resident) ----
    const float4* base = (const float4*)part + (size_t)n * SEGS * 128 + lane * 2;
    float4 A = make_float4(0.f, 0.f, 0.f, 0.f);
    float4 B = make_float4(0.f, 0.f, 0.f, 0.f);
    for (int s = 0; s < seg; ++s) {          // wave-uniform trip count
        float4 a = base[(size_t)s * 128];
        float4 b = base[(size_t)s * 128 + 1];
        A.x += a.x; A.y += a.y; A.z += a.z; A.w += a.w;
        B.x += b.x; B.y += b.y; B.z += b.z; B.w += b.w;
    }
    float4 acc = make_float4(A.x, A.z, B.x, B.z);
    float4 cnt = make_float4(A.y, A.w, B.y, B.w);

    // ---- dem MLP (wave-uniform; scalar-load friendly) ----
    float4 e4q;
    {
        const float* dn = dem + n * DEMD;
        float d[DEMD];
#pragma unroll
        for (int i = 0; i < DEMD; ++i)
            d[i] = dn[i];
        const int q = (lane < 5) ? lane : 0;
        float e0 = b2[q * 4 + 0], e1 = b2[q * 4 + 1], e2 = b2[q * 4 + 2], e3 = b2[q * 4 + 3];
#pragma unroll
        for (int k = 0; k < H1; ++k) {
            float hk = b1[k];
#pragma unroll
            for (int i = 0; i < DEMD; ++i)
                hk += d[i] * W1[i * H1 + k];
            hk = fmaxf(hk, 0.f);
            e0 += hk * W2[k * H2 + q * 4 + 0];
            e1 += hk * W2[k * H2 + q * 4 + 1];
            e2 += hk * W2[k * H2 + q * 4 + 2];
            e3 += hk * W2[k * H2 + q * 4 + 3];
        }
        e4q = make_float4(fmaxf(e0, 0.f), fmaxf(e1, 0.f), fmaxf(e2, 0.f), fmaxf(e3, 0.f));
    }

    // ---- stream 32 rows (MALL-resident), scan, NT-store ----
    const float4* tp = (const float4*)(ts + ((size_t)n * LL + seg * SROWS) * CIN) + lane;
    float* oprow = out + ((size_t)n * LL + seg * SROWS) * COUT;

    float4 v[2][UB];
#pragma unroll
    for (int u = 0; u < UB; ++u)
        v[0][u] = tp[(size_t)u * (CIN / 4)];

    for (int bb = 0; bb < NBATCH; ++bb) {
        const int cur = bb & 1;
        if (bb + 1 < NBATCH) {
#pragma unroll
            for (int u = 0; u < UB; ++u)
                v[cur ^ 1][u] = tp[(size_t)((bb + 1) * UB + u) * (CIN / 4)];
        }
#pragma unroll
        for (int u = 0; u < UB; ++u) {
            float4 x = v[cur][u];
            float4 r;
            acc.x += x.x; cnt.x += (x.x != 0.f) ? 1.f : 0.f;
            acc.y += x.y; cnt.y += (x.y != 0.f) ? 1.f : 0.f;
            acc.z += x.z; cnt.z += (x.z != 0.f) ? 1.f : 0.f;
            acc.w += x.w; cnt.w += (x.w != 0.f) ? 1.f : 0.f;
            r.x = fmaxf(acc.x * __builtin_amdgcn_rcpf(fmaxf(cnt.x, 1.f)), 0.f);
            r.y = fmaxf(acc.y * __builtin_amdgcn_rcpf(fmaxf(cnt.y, 1.f)), 0.f);
            r.z = fmaxf(acc.z * __builtin_amdgcn_rcpf(fmaxf(cnt.z, 1.f)), 0.f);
            r.w = fmaxf(acc.w * __builtin_amdgcn_rcpf(fmaxf(cnt.w, 1.f)), 0.f);
            float* rowp = oprow + (size_t)(bb * UB + u) * COUT;
            nt_store4(rowp + lane * 4, r);             // channels 0..255
            if (lane < 5)
                nt_store4(rowp + CIN + lane * 4, e4q); // channels 256..275
        }
    }
}

extern "C" void kernel_launch(void* const* d_in, const int* in_sizes, int n_in,
                              void* d_out, int out_size, void* d_ws, size_t ws_size,
                              hipStream_t stream) {
    const float* ts  = (const float*)d_in[0];
    const float* dem = (const float*)d_in[1];
    const float* W1  = (const float*)d_in[2];
    const float* b1  = (const float*)d_in[3];
    const float* W2  = (const float*)d_in[4];
    const float* b2  = (const float*)d_in[5];
    float* out  = (float*)d_out;
    float* part = (float*)d_ws;   // 64*64*256*2 floats = 8.39 MB

    pme_part<<<NBLK, 256, 0, stream>>>(ts, part);
    pme_scan<<<NBLK, 256, 0, stream>>>(ts, part, dem, W1, b1, W2, b2, out);
}